// Round 5
// baseline (210.172 us; speedup 1.0000x reference)
//
#include <hip/hip_runtime.h>

typedef int v4i __attribute__((ext_vector_type(4)));

#define NIMG 64
#define Cc   64
#define NPIX 3136
#define W8SZ (9 * 4 * 64 * 16)   // 36864 B per packed weight tensor

#define RBK   4                  // output rows per block
#define TILES 14                 // 56 / RBK row-tiles per image
#define XROWS 8                  // RBK + 4 staged x rows
#define MROWS 6                  // RBK + 2 mid rows
#define WPITCH 80                // LDS bytes per pixel (64 data + 16 pad)
#define ROWP  (58 * WPITCH)      // LDS bytes per padded row = 4640

__device__ __forceinline__ float clamp8(float v) {
    return fminf(fmaxf(v, -128.f), 127.f);
}

// ---- pack OIHW fp32 weights into MFMA A-fragment order ---------------------
// dst[t][cb][lane][j] : co = cb*16 + (lane&15), ci = (lane>>4)*16 + j, t = kh*3+kw
__global__ __launch_bounds__(256) void qbb_pack_w(
    const float* __restrict__ w1, const float* __restrict__ w2,
    signed char* __restrict__ w8)
{
    int idx = blockIdx.x * 256 + threadIdx.x;    // 0 .. 2*W8SZ-1
    int tsel = idx / W8SZ;
    int r    = idx - tsel * W8SZ;
    const float* src = tsel ? w2 : w1;
    int j    = r & 15;
    int lane = (r >> 4) & 63;
    int cb   = (r >> 10) & 3;
    int t    = r >> 12;
    int co   = cb * 16 + (lane & 15);
    int ci   = ((lane >> 4) << 4) + j;
    w8[idx] = (signed char)(int)src[(co * 64 + ci) * 9 + t];
}

// ---- fully fused: stage x -> conv1+bn1 (mid in LDS) -> conv2+bn2+add -------
__global__ __launch_bounds__(512, 4) void qbb_fused(
    const float* __restrict__ x, const signed char* __restrict__ w8,
    const float* __restrict__ b1, const float* __restrict__ g1,
    const float* __restrict__ be1,
    const float* __restrict__ b2, const float* __restrict__ g2,
    const float* __restrict__ be2,
    const int* __restrict__ p_zx, const int* __restrict__ p_zm,
    const int* __restrict__ p_M0c1, const int* __restrict__ p_shc1,
    const int* __restrict__ M0b1, const int* __restrict__ shb1,
    const int* __restrict__ p_M0c2, const int* __restrict__ p_shc2,
    const int* __restrict__ M0b2, const int* __restrict__ shb2,
    const int* __restrict__ p_M0a1, const int* __restrict__ p_sha1,
    const int* __restrict__ p_M0a2, const int* __restrict__ p_sha2,
    const int* __restrict__ p_zadd,
    float* __restrict__ out)
{
    __shared__ signed char xs[XROWS * ROWP];   // 37120 B: x-zx int8, padded
    __shared__ signed char ms[MROWS * ROWP];   // 27840 B: mid int8, padded

    const int tid  = threadIdx.x;
    const int lane = tid & 63, wid = tid >> 6;
    const int blk  = blockIdx.x;
    const int n    = blk / TILES;
    const int m0   = (blk - n * TILES) * RBK;  // first output row (content)

    const int cb = wid & 3;             // co-block per wave
    const int ws = wid >> 2;            // tile-half per wave (0/1)
    const int g  = lane >> 4, li = lane & 15;

    // ---- zero only the left/right pad columns (rows handled by staging) ----
    if (tid < 112) {
        if (tid < 64) {                 // xs: 8 rows x 2 cols x 4 chunks
            int r = tid >> 3, col = (tid >> 2) & 1, ch = tid & 3;
            *(v4i*)&xs[r * ROWP + (col * 57) * WPITCH + ch * 16] = v4i{0, 0, 0, 0};
        } else {                        // ms: 6 rows x 2 cols x 4 chunks
            int t2 = tid - 64;
            int r = t2 >> 3, col = (t2 >> 2) & 1, ch = t2 & 3;
            *(v4i*)&ms[r * ROWP + (col * 57) * WPITCH + ch * 16] = v4i{0, 0, 0, 0};
        }
    }

    // ---- A-fragments (global, L2-hot) and per-lane channel constants ----
    v4i a1[9], a2[9];
#pragma unroll
    for (int t = 0; t < 9; ++t) {
        a1[t] = *(const v4i*)(w8 + ((t * 4 + cb) * 64 + lane) * 16);
        a2[t] = *(const v4i*)(w8 + W8SZ + ((t * 4 + cb) * 64 + lane) * 16);
    }
    const float zx   = (float)(*p_zx);
    const float zm   = (float)(*p_zm);
    const float sc1  = ldexpf((float)(*p_M0c1), -31 - (*p_shc1));
    const float sc2  = ldexpf((float)(*p_M0c2), -31 - (*p_shc2));
    const float sa1  = ldexpf((float)(*p_M0a1), -31 - (*p_sha1));
    const float sa2  = ldexpf((float)(*p_M0a2), -31 - (*p_sha2));
    const float zadd = (float)(*p_zadd);
    float bb1[4], gg1[4], bev1[4], sb1[4];
    float bb2[4], gg2[4], bev2[4], sb2[4];
#pragma unroll
    for (int r = 0; r < 4; ++r) {
        int co = cb * 16 + (g << 2) + r;
        bb1[r] = b1[co]; gg1[r] = g1[co]; bev1[r] = be1[co];
        sb1[r] = ldexpf((float)M0b1[co], -31 - shb1[co]);
        bb2[r] = b2[co]; gg2[r] = g2[co]; bev2[r] = be2[co];
        sb2[r] = ldexpf((float)M0b2[co], -31 - shb2[co]);
    }

    // ---- stage x rows m0-2 .. m0+5 as int8 (x - zx); OOB rows -> zeros ----
    for (int e = tid; e < XROWS * 16 * 56; e += 512) {
        int L   = e / (16 * 56);
        int rem = e - L * (16 * 56);
        int cq  = rem / 56;
        int w   = rem - cq * 56;
        int hh  = m0 - 2 + L;
        unsigned pk = 0;
        if ((unsigned)hh < 56u) {
            const float* xp = x + ((size_t)(n * Cc + cq * 4) * 56 + hh) * 56 + w;
#pragma unroll
            for (int j = 0; j < 4; ++j) {
                int bv = (int)(xp[(size_t)j * NPIX] - zx);
                pk |= (unsigned)(bv & 255) << (8 * j);
            }
        }
        *(unsigned*)&xs[L * ROWP + (w + 1) * WPITCH + cq * 4] = pk;
    }
    __syncthreads();   // xs (and pad cols) ready

    // ---- conv1 + requant + bn1 + requant -> ms (int8), OOB rows masked ----
#define C1TILE(T)                                                              \
    {                                                                          \
        const int q  = (T) * 16 + li;                                          \
        const int rm = q / 56, w = q - rm * 56;                                \
        const signed char* bp = &xs[rm * ROWP + w * WPITCH + (g << 4)];        \
        v4i bf[9];                                                             \
        _Pragma("unroll")                                                      \
        for (int kh = 0; kh < 3; ++kh) {                                       \
            bf[kh * 3 + 0] = *(const v4i*)(bp + kh * ROWP);                    \
            bf[kh * 3 + 1] = *(const v4i*)(bp + kh * ROWP + WPITCH);           \
            bf[kh * 3 + 2] = *(const v4i*)(bp + kh * ROWP + 2 * WPITCH);       \
        }                                                                      \
        v4i acc = {0, 0, 0, 0};                                                \
        _Pragma("unroll")                                                      \
        for (int t = 0; t < 9; ++t)                                            \
            acc = __builtin_amdgcn_mfma_i32_16x16x64_i8(a1[t], bf[t], acc, 0, 0, 0); \
        const int m = m0 - 1 + rm;                                             \
        unsigned pk = 0;                                                       \
        if ((unsigned)m < 56u) {                                               \
            _Pragma("unroll")                                                  \
            for (int r = 0; r < 4; ++r) {                                      \
                float aa = (float)acc[r] + bb1[r];                             \
                float v  = clamp8(rintf(aa * sc1) + zm);                       \
                float tt = (v - zm) * gg1[r] + bev1[r];                        \
                float u  = clamp8(rintf(tt * sb1[r]) + zm);                    \
                pk |= (unsigned)((int)(u - zm) & 255) << (8 * r);              \
            }                                                                  \
        }                                                                      \
        *(unsigned*)&ms[rm * ROWP + (w + 1) * WPITCH + cb * 16 + (g << 2)] = pk; \
    }
    {
        int t = ws;
        for (; t + 2 < 21; t += 4) { C1TILE(t) C1TILE(t + 2) }
        if (t < 21) C1TILE(t)
    }
#undef C1TILE
    __syncthreads();   // ms ready

    // ---- conv2 + requant + bn2 + requant + shortcut add -> out (f32) ----
#define C2TILE(T)                                                              \
    {                                                                          \
        const int q = (T) * 16 + li;                                           \
        const int j = q / 56, w = q - j * 56;                                  \
        const signed char* bp = &ms[j * ROWP + w * WPITCH + (g << 4)];         \
        v4i bf[9];                                                             \
        _Pragma("unroll")                                                      \
        for (int kh = 0; kh < 3; ++kh) {                                       \
            bf[kh * 3 + 0] = *(const v4i*)(bp + kh * ROWP);                    \
            bf[kh * 3 + 1] = *(const v4i*)(bp + kh * ROWP + WPITCH);           \
            bf[kh * 3 + 2] = *(const v4i*)(bp + kh * ROWP + 2 * WPITCH);       \
        }                                                                      \
        v4i acc = {0, 0, 0, 0};                                                \
        _Pragma("unroll")                                                      \
        for (int t = 0; t < 9; ++t)                                            \
            acc = __builtin_amdgcn_mfma_i32_16x16x64_i8(a2[t], bf[t], acc, 0, 0, 0); \
        const int o = m0 + j;                                                  \
        unsigned id4 = *(const unsigned*)&xs[(j + 2) * ROWP + (w + 1) * WPITCH \
                                             + cb * 16 + (g << 2)];            \
        float* op = out + (size_t)(n * Cc + cb * 16 + (g << 2)) * NPIX         \
                        + o * 56 + w;                                          \
        _Pragma("unroll")                                                      \
        for (int r = 0; r < 4; ++r) {                                          \
            float aa   = (float)acc[r] + bb2[r];                               \
            float v    = clamp8(rintf(aa * sc2) + zm);                         \
            float tt   = (v - zm) * gg2[r] + bev2[r];                          \
            float u    = clamp8(rintf(tt * sb2[r]) + zm);                      \
            float outr = rintf((u - zm) * sa2);                                \
            float idr  = rintf((float)(signed char)(id4 >> (8 * r)) * sa1);    \
            op[(size_t)r * NPIX] = clamp8(idr + outr + zadd);                  \
        }                                                                      \
    }
    {
        int t = ws;
        for (; t + 2 < 14; t += 4) { C2TILE(t) C2TILE(t + 2) }
        if (t < 14) C2TILE(t)
    }
#undef C2TILE
}

extern "C" void kernel_launch(void* const* d_in, const int* in_sizes, int n_in,
                              void* d_out, int out_size, void* d_ws, size_t ws_size,
                              hipStream_t stream) {
    const float* x   = (const float*)d_in[0];
    const float* w1  = (const float*)d_in[1];
    const float* b1  = (const float*)d_in[2];
    const float* w2  = (const float*)d_in[3];
    const float* b2  = (const float*)d_in[4];
    const float* g1  = (const float*)d_in[5];
    const float* be1 = (const float*)d_in[6];
    const float* g2  = (const float*)d_in[7];
    const float* be2 = (const float*)d_in[8];
    const int* z_x   = (const int*)d_in[9];
    const int* z_mid = (const int*)d_in[10];
    const int* M0c1  = (const int*)d_in[11];
    const int* shc1  = (const int*)d_in[12];
    const int* M0b1  = (const int*)d_in[13];
    const int* shb1  = (const int*)d_in[14];
    const int* M0c2  = (const int*)d_in[15];
    const int* shc2  = (const int*)d_in[16];
    const int* M0b2  = (const int*)d_in[17];
    const int* shb2  = (const int*)d_in[18];
    const int* M0a1  = (const int*)d_in[19];
    const int* sha1  = (const int*)d_in[20];
    const int* M0a2  = (const int*)d_in[21];
    const int* sha2  = (const int*)d_in[22];
    const int* z_add = (const int*)d_in[23];

    signed char* w8 = (signed char*)d_ws;   // 2 x 36 KB packed A-fragments

    qbb_pack_w<<<dim3(2 * W8SZ / 256), dim3(256), 0, stream>>>(w1, w2, w8);
    qbb_fused<<<dim3(NIMG * TILES), dim3(512), 0, stream>>>(
        x, w8, b1, g1, be1, b2, g2, be2,
        z_x, z_mid, M0c1, shc1, M0b1, shb1, M0c2, shc2, M0b2, shb2,
        M0a1, sha1, M0a2, sha2, z_add, (float*)d_out);
}

// Round 6
// 209.989 us; speedup vs baseline: 1.0009x; 1.0009x over previous
//
#include <hip/hip_runtime.h>

typedef int v4i __attribute__((ext_vector_type(4)));

#define NIMG 64
#define Cc   64
#define NPIX 3136
#define W8SZ (9 * 4 * 64 * 16)   // 36864 B per packed weight tensor

#define RBK   4                  // output rows per block
#define TILES 14                 // 56 / RBK row-tiles per image
#define XROWS 8                  // RBK + 4 staged x rows
#define MROWS 6                  // RBK + 2 mid rows
#define WPITCH 80                // LDS bytes per pixel (64 data + 16 pad)
#define ROWP  (58 * WPITCH)      // LDS bytes per padded row = 4640

__device__ __forceinline__ float clamp8(float v) {
    return fminf(fmaxf(v, -128.f), 127.f);
}

// ---- pack OIHW fp32 weights into MFMA A-fragment order ---------------------
// dst[t][cb][lane][j] : co = cb*16 + (lane&15), ci = (lane>>4)*16 + j, t = kh*3+kw
__global__ __launch_bounds__(256) void qbb_pack_w(
    const float* __restrict__ w1, const float* __restrict__ w2,
    signed char* __restrict__ w8)
{
    int idx = blockIdx.x * 256 + threadIdx.x;    // 0 .. 2*W8SZ-1
    int tsel = idx / W8SZ;
    int r    = idx - tsel * W8SZ;
    const float* src = tsel ? w2 : w1;
    int j    = r & 15;
    int lane = (r >> 4) & 63;
    int cb   = (r >> 10) & 3;
    int t    = r >> 12;
    int co   = cb * 16 + (lane & 15);
    int ci   = ((lane >> 4) << 4) + j;
    w8[idx] = (signed char)(int)src[(co * 64 + ci) * 9 + t];
}

// ---- fully fused: stage x -> conv1+bn1 (mid in LDS) -> conv2+bn2+add -------
__global__ __launch_bounds__(512, 4) void qbb_fused(
    const float* __restrict__ x, const signed char* __restrict__ w8,
    const float* __restrict__ b1, const float* __restrict__ g1,
    const float* __restrict__ be1,
    const float* __restrict__ b2, const float* __restrict__ g2,
    const float* __restrict__ be2,
    const int* __restrict__ p_zx, const int* __restrict__ p_zm,
    const int* __restrict__ p_M0c1, const int* __restrict__ p_shc1,
    const int* __restrict__ M0b1, const int* __restrict__ shb1,
    const int* __restrict__ p_M0c2, const int* __restrict__ p_shc2,
    const int* __restrict__ M0b2, const int* __restrict__ shb2,
    const int* __restrict__ p_M0a1, const int* __restrict__ p_sha1,
    const int* __restrict__ p_M0a2, const int* __restrict__ p_sha2,
    const int* __restrict__ p_zadd,
    float* __restrict__ out)
{
    __shared__ signed char xs[XROWS * ROWP];   // 37120 B: x-zx int8, padded
    __shared__ signed char ms[MROWS * ROWP];   // 27840 B: mid int8, padded

    const int tid  = threadIdx.x;
    const int lane = tid & 63, wid = tid >> 6;
    const int blk  = blockIdx.x;
    const int n    = blk / TILES;
    const int m0   = (blk - n * TILES) * RBK;  // first output row (content)

    const int cb = wid & 3;             // co-block per wave
    const int ws = wid >> 2;            // tile-half per wave (0/1)
    const int g  = lane >> 4, li = lane & 15;

    // ---- zero only the left/right pad columns (rows handled by staging) ----
    if (tid < 112) {
        if (tid < 64) {                 // xs: 8 rows x 2 cols x 4 chunks
            int r = tid >> 3, col = (tid >> 2) & 1, ch = tid & 3;
            *(v4i*)&xs[r * ROWP + (col * 57) * WPITCH + ch * 16] = v4i{0, 0, 0, 0};
        } else {                        // ms: 6 rows x 2 cols x 4 chunks
            int t2 = tid - 64;
            int r = t2 >> 3, col = (t2 >> 2) & 1, ch = t2 & 3;
            *(v4i*)&ms[r * ROWP + (col * 57) * WPITCH + ch * 16] = v4i{0, 0, 0, 0};
        }
    }

    // ---- A-fragments (global, L2-hot) and per-lane channel constants ----
    v4i a1[9], a2[9];
#pragma unroll
    for (int t = 0; t < 9; ++t) {
        a1[t] = *(const v4i*)(w8 + ((t * 4 + cb) * 64 + lane) * 16);
        a2[t] = *(const v4i*)(w8 + W8SZ + ((t * 4 + cb) * 64 + lane) * 16);
    }
    const float zx   = (float)(*p_zx);
    const float zm   = (float)(*p_zm);
    const float sc1  = ldexpf((float)(*p_M0c1), -31 - (*p_shc1));
    const float sc2  = ldexpf((float)(*p_M0c2), -31 - (*p_shc2));
    const float sa1  = ldexpf((float)(*p_M0a1), -31 - (*p_sha1));
    const float sa2  = ldexpf((float)(*p_M0a2), -31 - (*p_sha2));
    const float zadd = (float)(*p_zadd);
    float bb1[4], gg1[4], bev1[4], sb1[4];
    float bb2[4], gg2[4], bev2[4], sb2[4];
#pragma unroll
    for (int r = 0; r < 4; ++r) {
        int co = cb * 16 + (g << 2) + r;
        bb1[r] = b1[co]; gg1[r] = g1[co]; bev1[r] = be1[co];
        sb1[r] = ldexpf((float)M0b1[co], -31 - shb1[co]);
        bb2[r] = b2[co]; gg2[r] = g2[co]; bev2[r] = be2[co];
        sb2[r] = ldexpf((float)M0b2[co], -31 - shb2[co]);
    }

    // ---- stage x rows m0-2 .. m0+5 as int8 (x - zx); OOB rows -> zeros ----
    for (int e = tid; e < XROWS * 16 * 56; e += 512) {
        int L   = e / (16 * 56);
        int rem = e - L * (16 * 56);
        int cq  = rem / 56;
        int w   = rem - cq * 56;
        int hh  = m0 - 2 + L;
        unsigned pk = 0;
        if ((unsigned)hh < 56u) {
            const float* xp = x + ((size_t)(n * Cc + cq * 4) * 56 + hh) * 56 + w;
#pragma unroll
            for (int j = 0; j < 4; ++j) {
                int bv = (int)(xp[(size_t)j * NPIX] - zx);
                pk |= (unsigned)(bv & 255) << (8 * j);
            }
        }
        *(unsigned*)&xs[L * ROWP + (w + 1) * WPITCH + cq * 4] = pk;
    }
    __syncthreads();   // xs (and pad cols) ready

    // ---- conv1 + requant + bn1 + requant -> ms (int8), OOB rows masked ----
#define C1TILE(T)                                                              \
    {                                                                          \
        const int q  = (T) * 16 + li;                                          \
        const int rm = q / 56, w = q - rm * 56;                                \
        const signed char* bp = &xs[rm * ROWP + w * WPITCH + (g << 4)];        \
        v4i bf[9];                                                             \
        _Pragma("unroll")                                                      \
        for (int kh = 0; kh < 3; ++kh) {                                       \
            bf[kh * 3 + 0] = *(const v4i*)(bp + kh * ROWP);                    \
            bf[kh * 3 + 1] = *(const v4i*)(bp + kh * ROWP + WPITCH);           \
            bf[kh * 3 + 2] = *(const v4i*)(bp + kh * ROWP + 2 * WPITCH);       \
        }                                                                      \
        v4i acc = {0, 0, 0, 0};                                                \
        _Pragma("unroll")                                                      \
        for (int t = 0; t < 9; ++t)                                            \
            acc = __builtin_amdgcn_mfma_i32_16x16x64_i8(a1[t], bf[t], acc, 0, 0, 0); \
        const int m = m0 - 1 + rm;                                             \
        unsigned pk = 0;                                                       \
        if ((unsigned)m < 56u) {                                               \
            _Pragma("unroll")                                                  \
            for (int r = 0; r < 4; ++r) {                                      \
                float aa = (float)acc[r] + bb1[r];                             \
                float v  = clamp8(rintf(aa * sc1) + zm);                       \
                float tt = (v - zm) * gg1[r] + bev1[r];                        \
                float u  = clamp8(rintf(tt * sb1[r]) + zm);                    \
                pk |= (unsigned)((int)(u - zm) & 255) << (8 * r);              \
            }                                                                  \
        }                                                                      \
        *(unsigned*)&ms[rm * ROWP + (w + 1) * WPITCH + cb * 16 + (g << 2)] = pk; \
    }
    {   // contiguous per-wave range: ws=0 -> 0..10, ws=1 -> 11..20
        const int lo = ws ? 11 : 0;
        const int hi = ws ? 21 : 11;
        int t = lo;
        for (; t + 1 < hi; t += 2) { C1TILE(t) C1TILE(t + 1) }
        if (t < hi) C1TILE(t)
    }
#undef C1TILE
    __syncthreads();   // ms ready

    // ---- conv2 + requant + bn2 + requant + shortcut add -> out (f32) ----
#define C2TILE(T)                                                              \
    {                                                                          \
        const int q = (T) * 16 + li;                                           \
        const int j = q / 56, w = q - j * 56;                                  \
        const signed char* bp = &ms[j * ROWP + w * WPITCH + (g << 4)];         \
        v4i bf[9];                                                             \
        _Pragma("unroll")                                                      \
        for (int kh = 0; kh < 3; ++kh) {                                       \
            bf[kh * 3 + 0] = *(const v4i*)(bp + kh * ROWP);                    \
            bf[kh * 3 + 1] = *(const v4i*)(bp + kh * ROWP + WPITCH);           \
            bf[kh * 3 + 2] = *(const v4i*)(bp + kh * ROWP + 2 * WPITCH);       \
        }                                                                      \
        v4i acc = {0, 0, 0, 0};                                                \
        _Pragma("unroll")                                                      \
        for (int t = 0; t < 9; ++t)                                            \
            acc = __builtin_amdgcn_mfma_i32_16x16x64_i8(a2[t], bf[t], acc, 0, 0, 0); \
        const int o = m0 + j;                                                  \
        unsigned id4 = *(const unsigned*)&xs[(j + 2) * ROWP + (w + 1) * WPITCH \
                                             + cb * 16 + (g << 2)];            \
        float* op = out + (size_t)(n * Cc + cb * 16 + (g << 2)) * NPIX         \
                        + o * 56 + w;                                          \
        _Pragma("unroll")                                                      \
        for (int r = 0; r < 4; ++r) {                                          \
            float aa   = (float)acc[r] + bb2[r];                               \
            float v    = clamp8(rintf(aa * sc2) + zm);                         \
            float tt   = (v - zm) * gg2[r] + bev2[r];                          \
            float u    = clamp8(rintf(tt * sb2[r]) + zm);                      \
            float outr = rintf((u - zm) * sa2);                                \
            float idr  = rintf((float)(signed char)(id4 >> (8 * r)) * sa1);    \
            op[(size_t)r * NPIX] = clamp8(idr + outr + zadd);                  \
        }                                                                      \
    }
    {   // contiguous per-wave range: ws=0 -> 0..6, ws=1 -> 7..13
        const int lo = ws ? 7 : 0;
        const int hi = ws ? 14 : 7;
        int t = lo;
        for (; t + 1 < hi; t += 2) { C2TILE(t) C2TILE(t + 1) }
        if (t < hi) C2TILE(t)
    }
#undef C2TILE
}

extern "C" void kernel_launch(void* const* d_in, const int* in_sizes, int n_in,
                              void* d_out, int out_size, void* d_ws, size_t ws_size,
                              hipStream_t stream) {
    const float* x   = (const float*)d_in[0];
    const float* w1  = (const float*)d_in[1];
    const float* b1  = (const float*)d_in[2];
    const float* w2  = (const float*)d_in[3];
    const float* b2  = (const float*)d_in[4];
    const float* g1  = (const float*)d_in[5];
    const float* be1 = (const float*)d_in[6];
    const float* g2  = (const float*)d_in[7];
    const float* be2 = (const float*)d_in[8];
    const int* z_x   = (const int*)d_in[9];
    const int* z_mid = (const int*)d_in[10];
    const int* M0c1  = (const int*)d_in[11];
    const int* shc1  = (const int*)d_in[12];
    const int* M0b1  = (const int*)d_in[13];
    const int* shb1  = (const int*)d_in[14];
    const int* M0c2  = (const int*)d_in[15];
    const int* shc2  = (const int*)d_in[16];
    const int* M0b2  = (const int*)d_in[17];
    const int* shb2  = (const int*)d_in[18];
    const int* M0a1  = (const int*)d_in[19];
    const int* sha1  = (const int*)d_in[20];
    const int* M0a2  = (const int*)d_in[21];
    const int* sha2  = (const int*)d_in[22];
    const int* z_add = (const int*)d_in[23];

    signed char* w8 = (signed char*)d_ws;   // 2 x 36 KB packed A-fragments

    qbb_pack_w<<<dim3(2 * W8SZ / 256), dim3(256), 0, stream>>>(w1, w2, w8);
    qbb_fused<<<dim3(NIMG * TILES), dim3(512), 0, stream>>>(
        x, w8, b1, g1, be1, b2, g2, be2,
        z_x, z_mid, M0c1, shc1, M0b1, shb1, M0c2, shc2, M0b2, shb2,
        M0a1, sha1, M0a2, sha2, z_add, (float*)d_out);
}